// Round 13
// baseline (154.070 us; speedup 1.0000x reference)
//
#include <hip/hip_runtime.h>
#include <hip/hip_fp16.h>
#include <math.h>

#define B_ 4
#define K_ 4
#define D_ 96
#define L_ 2048
#define N_ 16
#define R_ 6
#define C_ 38          // R + 2N
#define CH 32          // l's per thread in scan
#define TPR 64         // threads per row = L_/CH (one wave = one row)

__device__ __forceinline__ float softplus_f(float x) {
    return fmaxf(x, 0.f) + __logf(1.f + __expf(-fabsf(x)));
}

#if __has_builtin(__builtin_amdgcn_exp2f)
__device__ __forceinline__ float exp2_fast(float x) { return __builtin_amdgcn_exp2f(x); }
#else
__device__ __forceinline__ float exp2_fast(float x) { return __expf(0.6931471805599453f * x); }
#endif

__device__ __forceinline__ float h2f(const uint4& v, int e) {
    return __half2float(((const __half*)&v)[e]);
}

// BC layout (fp16, chunk-interleaved for CH=32 wave-coalesced scan reads):
//   uint4 (=8 halfs) at index (((bk*32 + i)*4 + j)*64 + t), where l = t*32+i
//   j=0: B n0..7   j=1: B n8..15   j=2: C n0..7   j=3: C n8..15

// ---------------------------------------------------------------------------
// Proj, d-split: grid (B*K, 16, 3), block 256 = 2 d-halves x 128 l's.
//   cg 0 -> B n0..15, cg 1 -> C n0..15, cg 2 -> dts r0..5.
// Each d-half computes a partial 16-row projection over 48 d's; halves
// combine via padded LDS. xs read 3x total (was 6x), per-thread chain halved.
// ---------------------------------------------------------------------------
__global__ __launch_bounds__(256) void proj_kernel(
    const float* __restrict__ xs, const float* __restrict__ xpw,
    uint4* __restrict__ BCc, float* __restrict__ dts_ws)
{
    __shared__ float sWt[2][48][16];    // 6 KB
    __shared__ float sAcc[128][17];     // 8.7 KB, stride 17 -> 2-way max
    const int bk = blockIdx.x;
    const int k = bk & 3;
    const int cg = blockIdx.z;
    const int tid = threadIdx.x;
    const int dh = tid >> 7;            // d-half 0/1
    const int lt = tid & 127;

    const int c0 = (cg == 0) ? R_ : (cg == 1) ? (R_ + N_) : 0;
    const int nr = (cg == 2) ? R_ : 16;

    for (int i = tid; i < 2 * 48 * 16; i += 256) {
        const int hh = i / 768, rem = i % 768, r = rem / 48, dd = rem % 48;
        sWt[hh][dd][r] = (r < nr) ? xpw[(k * C_ + c0 + r) * D_ + hh * 48 + dd] : 0.f;
    }
    __syncthreads();

    const int l = blockIdx.y * 128 + lt;
    const float* Xl = xs + (size_t)bk * D_ * L_ + (size_t)(dh * 48) * L_ + l;

    float acc[16];
#pragma unroll
    for (int r = 0; r < 16; ++r) acc[r] = 0.f;

#pragma unroll
    for (int dd = 0; dd < 48; ++dd) {
        const float xv = Xl[dd * L_];
        const float4 w0 = *(const float4*)&sWt[dh][dd][0];
        const float4 w1 = *(const float4*)&sWt[dh][dd][4];
        const float4 w2 = *(const float4*)&sWt[dh][dd][8];
        const float4 w3 = *(const float4*)&sWt[dh][dd][12];
        acc[0]  = fmaf(w0.x, xv, acc[0]);  acc[1]  = fmaf(w0.y, xv, acc[1]);
        acc[2]  = fmaf(w0.z, xv, acc[2]);  acc[3]  = fmaf(w0.w, xv, acc[3]);
        acc[4]  = fmaf(w1.x, xv, acc[4]);  acc[5]  = fmaf(w1.y, xv, acc[5]);
        acc[6]  = fmaf(w1.z, xv, acc[6]);  acc[7]  = fmaf(w1.w, xv, acc[7]);
        acc[8]  = fmaf(w2.x, xv, acc[8]);  acc[9]  = fmaf(w2.y, xv, acc[9]);
        acc[10] = fmaf(w2.z, xv, acc[10]); acc[11] = fmaf(w2.w, xv, acc[11]);
        acc[12] = fmaf(w3.x, xv, acc[12]); acc[13] = fmaf(w3.y, xv, acc[13]);
        acc[14] = fmaf(w3.z, xv, acc[14]); acc[15] = fmaf(w3.w, xv, acc[15]);
    }

    if (dh == 1) {
#pragma unroll
        for (int r = 0; r < 16; ++r) sAcc[lt][r] = acc[r];
    }
    __syncthreads();
    if (dh == 0) {
#pragma unroll
        for (int r = 0; r < 16; ++r) acc[r] += sAcc[lt][r];

        if (cg < 2) {
            const int i32 = l & 31, t32 = l >> 5;
            const int j0 = (cg == 0) ? 0 : 2;
            union { __half h[8]; uint4 v; } p0, p1;
#pragma unroll
            for (int e = 0; e < 8; ++e) {
                p0.h[e] = __float2half(acc[e]);
                p1.h[e] = __float2half(acc[8 + e]);
            }
            BCc[(((size_t)bk * 32 + i32) * 4 + j0) * TPR + t32] = p0.v;
            BCc[(((size_t)bk * 32 + i32) * 4 + j0 + 1) * TPR + t32] = p1.v;
        } else {
#pragma unroll
            for (int r = 0; r < R_; ++r)
                dts_ws[((size_t)bk * R_ + r) * L_ + l] = acc[r];
        }
    }
}

// ---------------------------------------------------------------------------
// Scan, CH=32: grid B*K*D, block 128 = 2 waves; wave g owns n-half [8g,8g+8),
// lane t owns l in [t*32, t*32+32). ONE WAVE SPANS THE ROW: no cross-wave
// a/b fixup at all (h0 = shfl_up(b,1)). Phase-3 partials stream to LDS
// (no yv regs); x reloaded in phase 3 (L1-hot) to cap VGPR naturally.
// ---------------------------------------------------------------------------
__global__ __launch_bounds__(128) void scan_kernel(
    const float* __restrict__ xs, const float* __restrict__ A_logs,
    const float* __restrict__ Ds, const float* __restrict__ dtw,
    const float* __restrict__ dtb, const float* __restrict__ dts_ws,
    const uint4* __restrict__ BCc, float* __restrict__ out)
{
    __shared__ float sy[2][TPR * 33];   // [g][t*33 + i], 2-way max conflicts

    const int bkd = blockIdx.x;
    const int d = bkd % D_;
    const int bk = bkd / D_;
    const int k = bk & 3;
    const int kd = k * D_ + d;
    const int tid = threadIdx.x;
    const int g = tid >> 6;          // wave = n-half
    const int t = tid & 63;          // lane = chunk owner

    const uint4* BC = BCc + (size_t)bk * 32 * 4 * TPR;
    const int jB = g, jC = 2 + g;

    // delta chunk
    float del[CH];
    const float bias = dtb[kd];
#pragma unroll
    for (int j = 0; j < CH; ++j) del[j] = bias;
    const float* w2 = dtw + (size_t)kd * R_;
    const float4* dts4 = (const float4*)(dts_ws + (size_t)bk * R_ * L_);
#pragma unroll
    for (int r = 0; r < R_; ++r) {
        const float wr = w2[r];
#pragma unroll
        for (int q = 0; q < 8; ++q) {
            const float4 tv = dts4[r * (L_ / 4) + t * 8 + q];
            del[q * 4 + 0] = fmaf(wr, tv.x, del[q * 4 + 0]);
            del[q * 4 + 1] = fmaf(wr, tv.y, del[q * 4 + 1]);
            del[q * 4 + 2] = fmaf(wr, tv.z, del[q * 4 + 2]);
            del[q * 4 + 3] = fmaf(wr, tv.w, del[q * 4 + 3]);
        }
    }
#pragma unroll
    for (int j = 0; j < CH; ++j) del[j] = softplus_f(del[j]);

    float A2[8];
    const float* Ap = A_logs + (size_t)kd * N_ + g * 8;
#pragma unroll
    for (int n = 0; n < 8; ++n) A2[n] = -__expf(Ap[n]) * 1.44269504f;
    const float Dval = Ds[kd];

    const float4* xv4 = (const float4*)(xs + (size_t)bkd * L_);

    // Phase 1: per-chunk aggregate over this n-half
    float a[8], b[8];
#pragma unroll
    for (int n = 0; n < 8; ++n) { a[n] = 1.f; b[n] = 0.f; }
    {
        float x[CH];
#pragma unroll
        for (int q = 0; q < 8; ++q) *(float4*)&x[q * 4] = xv4[t * 8 + q];
#pragma unroll
        for (int i = 0; i < CH; ++i) {
            const uint4 cB = BC[(i * 4 + jB) * TPR + t];
            const float dl = del[i];
            const float dx = dl * x[i];
#pragma unroll
            for (int n = 0; n < 8; ++n) {
                const float dA = exp2_fast(dl * A2[n]);
                b[n] = fmaf(dA, b[n], dx * h2f(cB, n));
                a[n] *= dA;
            }
        }
    }

    // Wave-level inclusive scan = the ENTIRE row scan (64 chunks)
#pragma unroll
    for (int off = 1; off < 64; off <<= 1) {
#pragma unroll
        for (int n = 0; n < 8; ++n) {
            const float pa = __shfl_up(a[n], off, 64);
            const float pb = __shfl_up(b[n], off, 64);
            if (t >= off) {
                b[n] = fmaf(a[n], pb, b[n]);
                a[n] *= pa;
            }
        }
    }

    // h0 = exclusive prefix (no cross-wave term!)
    float h[8];
#pragma unroll
    for (int n = 0; n < 8; ++n) {
        const float be = __shfl_up(b[n], 1, 64);
        h[n] = (t == 0) ? 0.f : be;
    }

    // Phase 3: re-run chunk with true initial state; stream partials to LDS
    {
        float x[CH];
#pragma unroll
        for (int q = 0; q < 8; ++q) *(float4*)&x[q * 4] = xv4[t * 8 + q];
#pragma unroll
        for (int i = 0; i < CH; ++i) {
            const uint4 cB = BC[(i * 4 + jB) * TPR + t];
            const uint4 cC = BC[(i * 4 + jC) * TPR + t];
            const float dl = del[i];
            const float dx = dl * x[i];
            float y = (g == 0) ? Dval * x[i] : 0.f;
#pragma unroll
            for (int n = 0; n < 8; ++n) {
                const float dA = exp2_fast(dl * A2[n]);
                h[n] = fmaf(dA, h[n], dx * h2f(cB, n));
                y = fmaf(h[n], h2f(cC, n), y);
            }
            sy[g][t * 33 + i] = y;
        }
    }
    __syncthreads();

    // Cooperative combine + coalesced store: thread tid covers l = j*128 + tid
    float* op = out + (size_t)bkd * L_;
#pragma unroll
    for (int j = 0; j < 16; ++j) {
        const int l = j * 128 + tid;
        const int ti = l >> 5, ii = l & 31;
        op[l] = sy[0][ti * 33 + ii] + sy[1][ti * 33 + ii];
    }
}

extern "C" void kernel_launch(void* const* d_in, const int* in_sizes, int n_in,
                              void* d_out, int out_size, void* d_ws, size_t ws_size,
                              hipStream_t stream) {
    const float* xs = (const float*)d_in[0];       // (B,K,D,L)
    const float* A_logs = (const float*)d_in[1];   // (K*D, N)
    const float* Ds = (const float*)d_in[2];       // (K*D,)
    const float* dtw = (const float*)d_in[3];      // (K,D,R)
    const float* dtb = (const float*)d_in[4];      // (K,D)
    const float* xpw = (const float*)d_in[5];      // (K,C,D)
    float* out = (float*)d_out;                    // (B,K,D,L) fp32

    uint4* BCc = (uint4*)d_ws;                     // 16*32*4*64 uint4 = 2 MB
    float* dts_ws = (float*)(BCc + (size_t)B_ * K_ * 32 * 4 * TPR);  // 768 KB

    proj_kernel<<<dim3(B_ * K_, 16, 3), 256, 0, stream>>>(xs, xpw, BCc, dts_ws);
    scan_kernel<<<B_ * K_ * D_, 128, 0, stream>>>(
        xs, A_logs, Ds, dtw, dtb, dts_ws, BCc, out);
}

// Round 14
// 111.468 us; speedup vs baseline: 1.3822x; 1.3822x over previous
//
#include <hip/hip_runtime.h>
#include <hip/hip_fp16.h>
#include <math.h>

#define B_ 4
#define K_ 4
#define D_ 96
#define L_ 2048
#define N_ 16
#define R_ 6
#define C_ 38          // R + 2N
#define CH 16          // l's per thread in scan (measured optimum: 8->52us, 16->40us, 32->84us)
#define TPR 128        // threads per row = L_/CH

__device__ __forceinline__ float softplus_f(float x) {
    return fmaxf(x, 0.f) + __logf(1.f + __expf(-fabsf(x)));
}

#if __has_builtin(__builtin_amdgcn_exp2f)
__device__ __forceinline__ float exp2_fast(float x) { return __builtin_amdgcn_exp2f(x); }
#else
__device__ __forceinline__ float exp2_fast(float x) { return __expf(0.6931471805599453f * x); }
#endif

__device__ __forceinline__ float h2f(const uint4& v, int e) {
    return __half2float(((const __half*)&v)[e]);
}

// BC layout (fp16, chunk-interleaved for CH=16 wave-coalesced scan reads):
//   uint4 (=8 halfs) at index (((bk*16 + i)*4 + j)*128 + t), where l = t*16+i
//   j=0: B n0..7   j=1: B n8..15   j=2: C n0..7   j=3: C n8..15

// ---------------------------------------------------------------------------
// Proj (R12 verbatim): grid (B*K, 8, 6), block 256, one l per thread.
// ---------------------------------------------------------------------------
__global__ __launch_bounds__(256) void proj_kernel(
    const float* __restrict__ xs, const float* __restrict__ xpw,
    uint4* __restrict__ BCc, float* __restrict__ dts_ws)
{
    __shared__ float sWt[D_][8];
    const int bk = blockIdx.x;
    const int k = bk & 3;
    const int cg = blockIdx.z;
    const int tid = threadIdx.x;

    int c0, nr;
    if (cg < 4)       { c0 = R_ + cg * 8; nr = 8; }
    else if (cg == 4) { c0 = 0;           nr = 4; }
    else              { c0 = 4;           nr = 2; }

    for (int i = tid; i < 8 * D_; i += 256) {
        const int r = i / D_, dd = i % D_;          // global read coalesced over dd
        sWt[dd][r] = (r < nr) ? xpw[(k * C_ + c0 + r) * D_ + dd] : 0.f;
    }
    __syncthreads();

    const int l = blockIdx.y * 256 + tid;
    const float* Xl = xs + (size_t)bk * D_ * L_ + l;

    float acc[8];
#pragma unroll
    for (int r = 0; r < 8; ++r) acc[r] = 0.f;

#pragma unroll
    for (int d = 0; d < D_; ++d) {
        const float xv = Xl[d * L_];
        float4 w0 = *(const float4*)&sWt[d][0];
        float4 w1 = *(const float4*)&sWt[d][4];
        acc[0] = fmaf(w0.x, xv, acc[0]); acc[1] = fmaf(w0.y, xv, acc[1]);
        acc[2] = fmaf(w0.z, xv, acc[2]); acc[3] = fmaf(w0.w, xv, acc[3]);
        acc[4] = fmaf(w1.x, xv, acc[4]); acc[5] = fmaf(w1.y, xv, acc[5]);
        acc[6] = fmaf(w1.z, xv, acc[6]); acc[7] = fmaf(w1.w, xv, acc[7]);
    }

    if (cg < 4) {
        const int i8 = l & 15, t8 = l >> 4;
        union { __half h[8]; uint4 v; } p;
#pragma unroll
        for (int e = 0; e < 8; ++e) p.h[e] = __float2half(acc[e]);
        BCc[(((size_t)bk * 16 + i8) * 4 + cg) * TPR + t8] = p.v;
    } else {
        const int rbase = (cg == 4) ? 0 : 4;
        const int rcnt = (cg == 4) ? 4 : 2;
        for (int r = 0; r < rcnt; ++r)
            dts_ws[((size_t)bk * R_ + rbase + r) * L_ + l] = acc[r];
    }
}

// ---------------------------------------------------------------------------
// Scan (R12 verbatim), CH=16 two-pass: grid B*K*D, block 256 = 2 n-groups x
// 128 l-threads. Group g = tid>>7 owns n in [8g, 8g+8); t = tid&127 owns
// l in [t*16, t*16+16). Natural register allocation (no forced bounds).
// ---------------------------------------------------------------------------
__global__ __launch_bounds__(256) void scan_kernel(
    const float* __restrict__ xs, const float* __restrict__ A_logs,
    const float* __restrict__ Ds, const float* __restrict__ dtw,
    const float* __restrict__ dtb, const float* __restrict__ dts_ws,
    const uint4* __restrict__ BCc, float* __restrict__ out)
{
    __shared__ float sAw[4][8];
    __shared__ float sBw[4][8];
    __shared__ float sy[TPR][17];   // stride 17: worst 2-way conflict = free

    const int bkd = blockIdx.x;
    const int d = bkd % D_;
    const int bk = bkd / D_;
    const int k = bk & 3;
    const int kd = k * D_ + d;
    const int tid = threadIdx.x;
    const int g = tid >> 7;          // n-half 0/1
    const int t = tid & (TPR - 1);   // l-chunk owner
    const int lane = tid & 63;
    const int gw = tid >> 6;         // wave 0..3; group g owns waves 2g, 2g+1

    const uint4* BC = BCc + (size_t)bk * 16 * 4 * TPR;
    const int jB = g, jC = 2 + g;

    // xs chunk -> registers (4x float4)
    const float4* xv4 = (const float4*)(xs + (size_t)bkd * L_);
    float x[CH];
#pragma unroll
    for (int q = 0; q < 4; ++q)
        *(float4*)&x[q * 4] = xv4[t * 4 + q];

    // delta chunk
    float del[CH];
    const float bias = dtb[kd];
#pragma unroll
    for (int j = 0; j < CH; ++j) del[j] = bias;
    const float* w2 = dtw + (size_t)kd * R_;
    const float4* dts4 = (const float4*)(dts_ws + (size_t)bk * R_ * L_);
#pragma unroll
    for (int r = 0; r < R_; ++r) {
        const float wr = w2[r];
#pragma unroll
        for (int q = 0; q < 4; ++q) {
            const float4 tv = dts4[r * (L_ / 4) + t * 4 + q];
            del[q * 4 + 0] = fmaf(wr, tv.x, del[q * 4 + 0]);
            del[q * 4 + 1] = fmaf(wr, tv.y, del[q * 4 + 1]);
            del[q * 4 + 2] = fmaf(wr, tv.z, del[q * 4 + 2]);
            del[q * 4 + 3] = fmaf(wr, tv.w, del[q * 4 + 3]);
        }
    }
#pragma unroll
    for (int j = 0; j < CH; ++j) del[j] = softplus_f(del[j]);

    float A2[8];
    const float* Ap = A_logs + (size_t)kd * N_ + g * 8;
#pragma unroll
    for (int n = 0; n < 8; ++n) A2[n] = -__expf(Ap[n]) * 1.44269504f;
    const float Dval = Ds[kd];

    // Phase 1: per-chunk aggregate over this n-half
    float a[8], b[8];
#pragma unroll
    for (int n = 0; n < 8; ++n) { a[n] = 1.f; b[n] = 0.f; }
#pragma unroll
    for (int i = 0; i < CH; ++i) {
        const uint4 cB = BC[(i * 4 + jB) * TPR + t];
        const float dl = del[i];
        const float dx = dl * x[i];
#pragma unroll
        for (int n = 0; n < 8; ++n) {
            const float dA = exp2_fast(dl * A2[n]);
            b[n] = fmaf(dA, b[n], dx * h2f(cB, n));
            a[n] *= dA;
        }
    }

    // Phase 2a: wave-level inclusive scan (8 n's)
#pragma unroll
    for (int off = 1; off < 64; off <<= 1) {
#pragma unroll
        for (int n = 0; n < 8; ++n) {
            const float pa = __shfl_up(a[n], off, 64);
            const float pb = __shfl_up(b[n], off, 64);
            if (lane >= off) {
                b[n] = fmaf(a[n], pb, b[n]);
                a[n] *= pa;
            }
        }
    }
    // Phase 2b: cross-wave fixup (2 waves per group)
    if (lane == 63) {
#pragma unroll
        for (int n = 0; n < 8; ++n) { sAw[gw][n] = a[n]; sBw[gw][n] = b[n]; }
    }
    __syncthreads();

    // h0 = state entering this thread's chunk
    float h[8];
#pragma unroll
    for (int n = 0; n < 8; ++n) {
        float ae = __shfl_up(a[n], 1, 64);
        float be = __shfl_up(b[n], 1, 64);
        if (lane == 0) { ae = 1.f; be = 0.f; }
        float wb = 0.f;
        for (int w = g * 2; w < gw; ++w) wb = fmaf(sAw[w][n], wb, sBw[w][n]);
        h[n] = fmaf(ae, wb, be);
    }

    // Phase 3: re-run chunk with true initial state; partial y per group
    float yv[CH];
#pragma unroll
    for (int i = 0; i < CH; ++i) {
        const uint4 cB = BC[(i * 4 + jB) * TPR + t];
        const uint4 cC = BC[(i * 4 + jC) * TPR + t];
        const float dl = del[i];
        const float dx = dl * x[i];
        float y = (g == 0) ? Dval * x[i] : 0.f;
#pragma unroll
        for (int n = 0; n < 8; ++n) {
            const float dA = exp2_fast(dl * A2[n]);
            h[n] = fmaf(dA, h[n], dx * h2f(cB, n));
            y = fmaf(h[n], h2f(cC, n), y);
        }
        yv[i] = y;
    }

    // Combine group partials and store
    if (g == 1) {
#pragma unroll
        for (int j = 0; j < CH; ++j) sy[t][j] = yv[j];
    }
    __syncthreads();
    if (g == 0) {
#pragma unroll
        for (int j = 0; j < CH; ++j) yv[j] += sy[t][j];
        float4* ov = (float4*)(out + (size_t)bkd * L_);
#pragma unroll
        for (int q = 0; q < 4; ++q)
            ov[t * 4 + q] = make_float4(yv[q * 4], yv[q * 4 + 1],
                                        yv[q * 4 + 2], yv[q * 4 + 3]);
    }
}

extern "C" void kernel_launch(void* const* d_in, const int* in_sizes, int n_in,
                              void* d_out, int out_size, void* d_ws, size_t ws_size,
                              hipStream_t stream) {
    const float* xs = (const float*)d_in[0];       // (B,K,D,L)
    const float* A_logs = (const float*)d_in[1];   // (K*D, N)
    const float* Ds = (const float*)d_in[2];       // (K*D,)
    const float* dtw = (const float*)d_in[3];      // (K,D,R)
    const float* dtb = (const float*)d_in[4];      // (K,D)
    const float* xpw = (const float*)d_in[5];      // (K,C,D)
    float* out = (float*)d_out;                    // (B,K,D,L) fp32

    uint4* BCc = (uint4*)d_ws;                     // 16*16*4*128 uint4 = 2 MB
    float* dts_ws = (float*)(BCc + (size_t)B_ * K_ * 16 * 4 * TPR);  // 768 KB

    proj_kernel<<<dim3(B_ * K_, 8, 6), 256, 0, stream>>>(xs, xpw, BCc, dts_ws);
    scan_kernel<<<B_ * K_ * D_, 256, 0, stream>>>(
        xs, A_logs, Ds, dtw, dtb, dts_ws, BCc, out);
}